// Round 7
// baseline (188.924 us; speedup 1.0000x reference)
//
#include <hip/hip_runtime.h>
#include <stdint.h>

// Problem constants (from reference setup_inputs)
#define BB 4
#define SS 512
#define EE 64
#define VV 50257
#define KK 250              // k_val
#define NROWS (BB * SS)     // 2048
#define SEG 1024            // per-half-row-block candidate segment
// STEP_SIZE = 0.1 -> multiply by 10; TEMP = 1.0 -> no-op

// Float-domain pre-filter threshold. P(N(0,1) >= 2.4) = 0.0082 -> E[412]/row,
// sigma ~20. Correctness does NOT depend on it: rows with <KK survivors or a
// segment overflow take an exact full-row fallback in select_kernel.
#define THRF 2.4f
#define POISON 0xFFFFFFFFu

typedef float float4n __attribute__((ext_vector_type(4)));

__device__ __forceinline__ unsigned fkey(float f) {
    // monotonic map: larger float -> larger unsigned
    unsigned u = __float_as_uint(f);
    return (u & 0x80000000u) ? ~u : (u | 0x80000000u);
}

// ---------------- kernel 1: streaming filter, half-row per block ----------------
// Survivors buffered in LDS; flushed to a PRIVATE global segment; count stored
// non-atomically. No global atomics, no pre-zeroed state.
__global__ __launch_bounds__(256, 8)
void filter_kernel(const float* __restrict__ lg,
                   unsigned long long* __restrict__ cand,
                   unsigned* __restrict__ cnt)
{
    __shared__ unsigned long long lbuf[SEG];
    __shared__ unsigned lcnt;
    const int bid = blockIdx.x, tid = threadIdx.x;
    const int row = bid >> 1, half = bid & 1;
    if (tid == 0) lcnt = 0u;
    __syncthreads();

    const size_t rowbase = (size_t)row * VV;
    const unsigned p  = (4u - ((unsigned)rowbase & 3u)) & 3u;  // peel to 16B align
    const unsigned F  = (VV - p) >> 2;                         // aligned float4 count
    const unsigned F0 = F >> 1;
    const float4n* rp4 = (const float4n*)(lg + rowbase + p);

    auto emit = [&](float f, unsigned col) {
        if (f >= THRF) {
            unsigned q = atomicAdd(&lcnt, 1u);
            if (q < SEG)
                lbuf[q] = ((unsigned long long)fkey(f) << 32) | (unsigned)(~col);
        }
    };
    auto emit4 = [&](float4n v, unsigned c0) {
        float m = fmaxf(fmaxf(v.x, v.y), fmaxf(v.z, v.w));
        if (m >= THRF) {
            emit(v.x, c0 + 0); emit(v.y, c0 + 1);
            emit(v.z, c0 + 2); emit(v.w, c0 + 3);
        }
    };

    const unsigned lo = half ? F0 : 0u;
    const unsigned hi = half ? F  : F0;

    if (half == 0 && tid < (int)p) emit(lg[rowbase + tid], tid);   // peel scalars

    unsigned i = lo + tid;
    for (; i + 1792u < hi; i += 2048u) {       // 8 loads in flight
        float4n v0 = __builtin_nontemporal_load(&rp4[i]);
        float4n v1 = __builtin_nontemporal_load(&rp4[i + 256u]);
        float4n v2 = __builtin_nontemporal_load(&rp4[i + 512u]);
        float4n v3 = __builtin_nontemporal_load(&rp4[i + 768u]);
        float4n v4 = __builtin_nontemporal_load(&rp4[i + 1024u]);
        float4n v5 = __builtin_nontemporal_load(&rp4[i + 1280u]);
        float4n v6 = __builtin_nontemporal_load(&rp4[i + 1536u]);
        float4n v7 = __builtin_nontemporal_load(&rp4[i + 1792u]);
        emit4(v0, p + 4u * i);
        emit4(v1, p + 4u * (i + 256u));
        emit4(v2, p + 4u * (i + 512u));
        emit4(v3, p + 4u * (i + 768u));
        emit4(v4, p + 4u * (i + 1024u));
        emit4(v5, p + 4u * (i + 1280u));
        emit4(v6, p + 4u * (i + 1536u));
        emit4(v7, p + 4u * (i + 1792u));
    }
    for (; i < hi; i += 256u) {
        float4n v = __builtin_nontemporal_load(&rp4[i]);
        emit4(v, p + 4u * i);
    }
    if (half == 1) {                                              // tail scalars
        for (unsigned t = p + 4u * F + tid; t < VV; t += 256u) emit(lg[rowbase + t], t);
    }

    __syncthreads();
    const unsigned total = lcnt;
    const unsigned m = total > SEG ? SEG : total;
    for (unsigned j = tid; j < m; j += 256u)
        cand[(size_t)bid * SEG + j] = lbuf[j];
    if (tid == 0)
        cnt[bid] = (total > SEG) ? POISON : total;   // poison -> exact fallback
}

// ---------------- kernel 2: per-row prune + sort + epilogue ----------------
__global__ __launch_bounds__(256, 4)
void select_kernel(const float* __restrict__ gx,
                   const float* __restrict__ cb,
                   const float* __restrict__ W,
                   const float* __restrict__ logits,
                   const unsigned long long* __restrict__ cand,
                   const unsigned* __restrict__ cnt,
                   float* __restrict__ out0,   // filtered [B*S, K]
                   float* __restrict__ out1)   // ids as float [B*S, K]
{
    __shared__ unsigned long long cs[2 * SEG];   // 16 KB candidates
    __shared__ unsigned long long sbuf[512];     // 4 KB pruned sort buffer
    __shared__ unsigned hist4[4096];             // 16 KB dedicated histogram
    __shared__ unsigned chunkSum[256];
    __shared__ float gx_s[EE], cb_s[EE];
    __shared__ unsigned sThreshBin, sThreshKey, sCnt, sCnt2;

    const int row = blockIdx.x;
    const int tid = threadIdx.x;
    const float* rp = logits + (size_t)row * VV;

    if (tid < EE) {
        gx_s[tid] = gx[(size_t)row * EE + tid];
        cb_s[tid] = cb[(size_t)row * EE + tid];
    }
    for (int i = tid; i < 4096; i += 256) hist4[i] = 0u;
    if (tid == 0) { sCnt = 0u; sCnt2 = 0u; }

    const unsigned c0 = cnt[2 * row], c1 = cnt[2 * row + 1];
    const bool segs_ok = (c0 <= SEG) && (c1 <= SEG);
    const unsigned n = segs_ok ? c0 + c1 : 0u;

    unsigned long long* srt;
    unsigned P;

    if (segs_ok && n >= KK) {
        // ================= FAST PATH =================
        for (unsigned i = tid; i < c0; i += 256)
            cs[i] = cand[(size_t)(2 * row) * SEG + i];
        for (unsigned i = tid; i < c1; i += 256)
            cs[c0 + i] = cand[(size_t)(2 * row + 1) * SEG + i];
        __syncthreads();

        // fine histogram: bins on fkey bits [31:16] - 49152 (all cands >= 2.4
        // -> bin >= 25); clamp huge values into last bin
        for (unsigned i = tid; i < n; i += 256) {
            unsigned b = (((unsigned)(cs[i] >> 32)) >> 16) - 49152u;
            if (b > 4095u) b = 4095u;
            atomicAdd(&hist4[b], 1u);
        }
        __syncthreads();

        {
            unsigned csum = 0;
            #pragma unroll
            for (int b = 0; b < 16; ++b) csum += hist4[tid * 16 + b];
            chunkSum[tid] = csum;
        }
        __syncthreads();
        {
            unsigned g = 0;
            for (int u = tid + 1; u < 256; ++u) g += chunkSum[u];
            unsigned csm = chunkSum[tid];
            if (g < KK && g + csm >= KK) {
                unsigned cum = g;
                #pragma unroll
                for (int b = 15; b >= 0; --b) {
                    unsigned c = hist4[tid * 16 + b];
                    if (cum + c >= KK) { sThreshBin = (unsigned)(tid * 16 + b); break; }
                    cum += c;
                }
            }
        }
        __syncthreads();
        const unsigned Tbin = sThreshBin;
        __syncthreads();

        // compact survivors (bin >= Tbin, ~250 + threshold-bin width ~5)
        for (unsigned i = tid; i < n; i += 256) {
            unsigned b = (((unsigned)(cs[i] >> 32)) >> 16) - 49152u;
            if (b > 4095u) b = 4095u;
            if (b >= Tbin) {
                unsigned q = atomicAdd(&sCnt2, 1u);
                if (q < 512) sbuf[q] = cs[i];
            }
        }
        __syncthreads();
        const unsigned nc = sCnt2;
        if (nc <= 512) {
            srt = sbuf;
            P = 256; while (P < nc) P <<= 1;
            for (unsigned i = nc + tid; i < P; i += 256) sbuf[i] = 0ull;
        } else {
            // threshold bin unusually fat: sort all candidates
            srt = cs;
            P = 256; while (P < n) P <<= 1;
            for (unsigned i = n + tid; i < P; i += 256) cs[i] = 0ull;
        }
        __syncthreads();
    } else {
        // ====== EXACT FALLBACK: full-row rescan (never taken on N(0,1)) ======
        __syncthreads();   // hist4 zeroed above

        const unsigned p  = (4u - ((unsigned)((size_t)row * VV) & 3u)) & 3u;
        const unsigned nb = (VV - p) >> 2;
        const unsigned tail0 = p + nb * 4u;
        const float4n* rp4 = (const float4n*)(rp + p);

        if (tid < (int)p) atomicAdd(&hist4[fkey(rp[tid]) >> 20], 1u);
        for (unsigned i = tid; i < nb; i += 256) {
            float4n v = rp4[i];
            atomicAdd(&hist4[fkey(v.x) >> 20], 1u);
            atomicAdd(&hist4[fkey(v.y) >> 20], 1u);
            atomicAdd(&hist4[fkey(v.z) >> 20], 1u);
            atomicAdd(&hist4[fkey(v.w) >> 20], 1u);
        }
        for (unsigned t = tail0 + tid; t < VV; t += 256) atomicAdd(&hist4[fkey(rp[t]) >> 20], 1u);
        __syncthreads();

        {
            unsigned csum = 0;
            #pragma unroll
            for (int b = 0; b < 16; ++b) csum += hist4[tid * 16 + b];
            chunkSum[tid] = csum;
        }
        __syncthreads();
        {
            unsigned g = 0;
            for (int u = tid + 1; u < 256; ++u) g += chunkSum[u];
            unsigned csm = chunkSum[tid];
            if (g < KK && g + csm >= KK) {
                unsigned cum = g;
                #pragma unroll
                for (int b = 15; b >= 0; --b) {
                    unsigned c = hist4[tid * 16 + b];
                    if (cum + c >= KK) { sThreshKey = ((unsigned)(tid * 16 + b)) << 20; break; }
                    cum += c;
                }
            }
        }
        __syncthreads();
        const unsigned keyT = sThreshKey;
        __syncthreads();

        auto emit2 = [&](unsigned k, unsigned idx) {
            if (k >= keyT) {
                unsigned q = atomicAdd(&sCnt, 1u);
                if (q < 2 * SEG) cs[q] = ((unsigned long long)k << 32) | (unsigned)(~idx);
            }
        };
        if (tid < (int)p) emit2(fkey(rp[tid]), tid);
        for (unsigned i = tid; i < nb; i += 256) {
            float4n v = rp4[i];
            unsigned ia = p + 4u * i;
            emit2(fkey(v.x), ia + 0); emit2(fkey(v.y), ia + 1);
            emit2(fkey(v.z), ia + 2); emit2(fkey(v.w), ia + 3);
        }
        for (unsigned t = tail0 + tid; t < VV; t += 256) emit2(fkey(rp[t]), t);
        __syncthreads();
        unsigned n1 = sCnt; if (n1 > 2 * SEG) n1 = 2 * SEG;
        srt = cs;
        P = 256; while (P < n1) P <<= 1;
        for (unsigned i = n1 + tid; i < P; i += 256) cs[i] = 0ull;
        __syncthreads();
    }

    // ---- bitonic sort descending on composite (key<<32 | ~idx) ----
    for (unsigned k = 2; k <= P; k <<= 1) {
        for (unsigned jj = k >> 1; jj > 0; jj >>= 1) {
            for (unsigned i2 = tid; i2 < P; i2 += 256) {
                unsigned l = i2 ^ jj;
                if (l > i2) {
                    unsigned long long a = srt[i2], b = srt[l];
                    bool up = ((i2 & k) == 0);
                    if (up ? (a < b) : (a > b)) { srt[i2] = b; srt[l] = a; }
                }
            }
            __syncthreads();
        }
    }

    // ---- epilogue: proposal value at the K selected ids ----
    if (tid < KK) {
        float gxcb = 0.f, cbn = 0.f;
        #pragma unroll
        for (int e = 0; e < EE; ++e) { gxcb += gx_s[e] * cb_s[e]; cbn += cb_s[e] * cb_s[e]; }

        unsigned long long ck = srt[tid];
        unsigned v = ~((unsigned)ck);
        const float4* Wv = (const float4*)(W + (size_t)v * EE);
        float d1 = 0.f, d2 = 0.f, wn = 0.f;
        #pragma unroll
        for (int j2 = 0; j2 < 16; ++j2) {
            float4 w = Wv[j2];
            float a0 = gx_s[4*j2+0], a1 = gx_s[4*j2+1], a2 = gx_s[4*j2+2], a3 = gx_s[4*j2+3];
            float b0 = cb_s[4*j2+0], b1 = cb_s[4*j2+1], b2 = cb_s[4*j2+2], b3 = cb_s[4*j2+3];
            d1 += a0*w.x + a1*w.y + a2*w.z + a3*w.w;
            d2 += b0*w.x + b1*w.y + b2*w.z + b3*w.w;
            wn += w.x*w.x + w.y*w.y + w.z*w.z + w.w*w.w;
        }
        // dist = 0.5*(t1_1 - t1_2) + (t2_1 - 2*t2_2 + t2_3)/0.1 ; out = -dist / TEMP
        float unf = -(0.5f * (d1 - gxcb) + (wn - 2.0f * d2 + cbn) * 10.0f);
        out0[(size_t)row * KK + tid] = unf;
        out1[(size_t)row * KK + tid] = (float)v;
    }
}

extern "C" void kernel_launch(void* const* d_in, const int* in_sizes, int n_in,
                              void* d_out, int out_size, void* d_ws, size_t ws_size,
                              hipStream_t stream) {
    const float* gx = (const float*)d_in[0];      // [B,S,E]
    const float* cb = (const float*)d_in[1];      // [B,S,E]
    const float* W  = (const float*)d_in[2];      // [V,E]
    const float* lg = (const float*)d_in[3];      // [B,S,V]
    float* out0 = (float*)d_out;                       // filtered, 512000 floats
    float* out1 = out0 + (size_t)BB * SS * KK;         // ids as float, 512000

    // d_ws layout: cnt[4096] u32 (32 KB pad) ; cand[4096][SEG] u64 (33.5 MB)
    unsigned* cnt = (unsigned*)d_ws;
    unsigned long long* cand = (unsigned long long*)((char*)d_ws + 32768);

    hipLaunchKernelGGL(filter_kernel, dim3(2 * NROWS), dim3(256), 0, stream,
                       lg, cand, cnt);
    hipLaunchKernelGGL(select_kernel, dim3(NROWS), dim3(256), 0, stream,
                       gx, cb, W, lg, cand, cnt, out0, out1);
}

// Round 8
// 137.124 us; speedup vs baseline: 1.3778x; 1.3778x over previous
//
#include <hip/hip_runtime.h>
#include <stdint.h>

// Problem constants (from reference setup_inputs)
#define BB 4
#define SS 512
#define EE 64
#define VV 50257
#define KK 250              // k_val
#define NROWS (BB * SS)     // 2048
#define FCAP 512            // per-half-row-block candidate segment capacity
// STEP_SIZE = 0.1 -> multiply by 10; TEMP = 1.0 -> no-op

// Float-domain pre-filter threshold. P(N(0,1) >= 2.4) = 0.0082 -> E[206]/half-row,
// sigma ~14 -> FCAP=512 is ~21 sigma. Correctness does NOT depend on it: rows
// with <KK survivors or a segment overflow take an exact full-row fallback.
#define THRF 2.4f
#define POISON 0xFFFFFFFFu

typedef float float4n __attribute__((ext_vector_type(4)));

__device__ __forceinline__ unsigned fkey(float f) {
    // monotonic map: larger float -> larger unsigned
    unsigned u = __float_as_uint(f);
    return (u & 0x80000000u) ? ~u : (u | 0x80000000u);
}

// ---------------- kernel 1: streaming filter, half-row per block ----------------
// Round-6 loop structure (4 loads in flight, 16-wide max guard). Survivors
// buffered in LDS; flushed to a PRIVATE global segment; count stored
// non-atomically (no global atomics, no pre-zeroed state, no zero_cnt pass).
__global__ __launch_bounds__(256, 8)
void filter_kernel(const float* __restrict__ lg,
                   unsigned long long* __restrict__ cand,
                   unsigned* __restrict__ cnt)
{
    __shared__ unsigned long long lbuf[FCAP];
    __shared__ unsigned lcnt;
    const int bid = blockIdx.x, tid = threadIdx.x;
    const int row = bid >> 1, half = bid & 1;
    if (tid == 0) lcnt = 0u;
    __syncthreads();

    const size_t rowbase = (size_t)row * VV;
    const unsigned p  = (4u - ((unsigned)rowbase & 3u)) & 3u;  // peel to 16B align
    const unsigned F  = (VV - p) >> 2;                         // aligned float4 count
    const unsigned F0 = F >> 1;
    const float4n* rp4 = (const float4n*)(lg + rowbase + p);

    auto emit = [&](float f, unsigned col) {
        if (f >= THRF) {
            unsigned q = atomicAdd(&lcnt, 1u);
            if (q < FCAP)
                lbuf[q] = ((unsigned long long)fkey(f) << 32) | (unsigned)(~col);
        }
    };

    const unsigned lo = half ? F0 : 0u;
    const unsigned hi = half ? F  : F0;

    if (half == 0 && tid < (int)p) emit(lg[rowbase + tid], tid);   // peel scalars

    unsigned i = lo + tid;
    for (; i + 768u < hi; i += 1024u) {        // 4 loads in flight (round-6 form)
        float4n a = __builtin_nontemporal_load(&rp4[i]);
        float4n b = __builtin_nontemporal_load(&rp4[i + 256u]);
        float4n c = __builtin_nontemporal_load(&rp4[i + 512u]);
        float4n d = __builtin_nontemporal_load(&rp4[i + 768u]);
        // 16-way max tree: 8 max3-friendly ops per 16 elements
        float t0 = fmaxf(fmaxf(a.x, a.y), a.z);
        float t1 = fmaxf(fmaxf(a.w, b.x), b.y);
        float t2 = fmaxf(fmaxf(b.z, b.w), c.x);
        float t3 = fmaxf(fmaxf(c.y, c.z), c.w);
        float t4 = fmaxf(fmaxf(d.x, d.y), d.z);
        float u0 = fmaxf(fmaxf(t0, t1), t2);
        float u1 = fmaxf(fmaxf(t3, t4), d.w);
        if (fmaxf(u0, u1) >= THRF) {
            unsigned c0 = p + 4u*i, c1 = p + 4u*(i+256u), c2 = p + 4u*(i+512u), c3 = p + 4u*(i+768u);
            emit(a.x, c0+0); emit(a.y, c0+1); emit(a.z, c0+2); emit(a.w, c0+3);
            emit(b.x, c1+0); emit(b.y, c1+1); emit(b.z, c1+2); emit(b.w, c1+3);
            emit(c.x, c2+0); emit(c.y, c2+1); emit(c.z, c2+2); emit(c.w, c2+3);
            emit(d.x, c3+0); emit(d.y, c3+1); emit(d.z, c3+2); emit(d.w, c3+3);
        }
    }
    for (; i < hi; i += 256u) {
        float4n a = __builtin_nontemporal_load(&rp4[i]);
        float m = fmaxf(fmaxf(a.x, a.y), fmaxf(a.z, a.w));
        if (m >= THRF) {
            unsigned c0 = p + 4u*i;
            emit(a.x, c0+0); emit(a.y, c0+1); emit(a.z, c0+2); emit(a.w, c0+3);
        }
    }
    if (half == 1) {                                              // tail scalars
        for (unsigned t = p + 4u * F + tid; t < VV; t += 256u) emit(lg[rowbase + t], t);
    }

    __syncthreads();
    const unsigned total = lcnt;
    const unsigned m = total > FCAP ? FCAP : total;
    for (unsigned j = tid; j < m; j += 256u)
        cand[(size_t)bid * FCAP + j] = lbuf[j];
    if (tid == 0)
        cnt[bid] = (total > FCAP) ? POISON : total;   // poison -> exact fallback
}

// ---------------- kernel 2: per-row direct sort + epilogue (round-6 form) ----------------
__global__ __launch_bounds__(256, 4)
void select_kernel(const float* __restrict__ gx,
                   const float* __restrict__ cb,
                   const float* __restrict__ W,
                   const float* __restrict__ logits,
                   const unsigned long long* __restrict__ cand,
                   const unsigned* __restrict__ cnt,
                   float* __restrict__ out0,   // filtered [B*S, K]
                   float* __restrict__ out1)   // ids as float [B*S, K]
{
    __shared__ unsigned long long cs[2048];    // 16 KB; fallback hist4[4096] aliases
    __shared__ unsigned chunkSum[256];
    __shared__ float gx_s[EE], cb_s[EE];
    __shared__ unsigned sThreshKey, sCnt;

    const int row = blockIdx.x;
    const int tid = threadIdx.x;
    const float* rp = logits + (size_t)row * VV;

    if (tid < EE) {
        gx_s[tid] = gx[(size_t)row * EE + tid];
        cb_s[tid] = cb[(size_t)row * EE + tid];
    }
    if (tid == 0) sCnt = 0u;

    const unsigned c0 = cnt[2 * row], c1 = cnt[2 * row + 1];
    const bool segs_ok = (c0 <= FCAP) && (c1 <= FCAP);
    const unsigned n = segs_ok ? c0 + c1 : 0u;

    unsigned P;

    if (segs_ok && n >= KK) {
        // ---- fast path: direct sort of <=1024 candidates (typically ~412) ----
        for (unsigned i = tid; i < c0; i += 256)
            cs[i] = cand[(size_t)(2 * row) * FCAP + i];
        for (unsigned i = tid; i < c1; i += 256)
            cs[c0 + i] = cand[(size_t)(2 * row + 1) * FCAP + i];
        P = 256; while (P < n) P <<= 1;
        for (unsigned i = n + tid; i < P; i += 256) cs[i] = 0ull;
        __syncthreads();
    } else {
        // ====== EXACT FALLBACK: full-row rescan (never taken on N(0,1)) ======
        unsigned* hist4 = (unsigned*)cs;       // 4096 bins alias cs (16 KB)
        for (int i = tid; i < 4096; i += 256) hist4[i] = 0u;
        __syncthreads();

        const unsigned p  = (4u - ((unsigned)((size_t)row * VV) & 3u)) & 3u;
        const unsigned nb = (VV - p) >> 2;
        const unsigned tail0 = p + nb * 4u;
        const float4n* rp4 = (const float4n*)(rp + p);

        if (tid < (int)p) atomicAdd(&hist4[fkey(rp[tid]) >> 20], 1u);
        for (unsigned i = tid; i < nb; i += 256) {
            float4n v = rp4[i];
            atomicAdd(&hist4[fkey(v.x) >> 20], 1u);
            atomicAdd(&hist4[fkey(v.y) >> 20], 1u);
            atomicAdd(&hist4[fkey(v.z) >> 20], 1u);
            atomicAdd(&hist4[fkey(v.w) >> 20], 1u);
        }
        for (unsigned t = tail0 + tid; t < VV; t += 256) atomicAdd(&hist4[fkey(rp[t]) >> 20], 1u);
        __syncthreads();

        {
            unsigned csum = 0;
            #pragma unroll
            for (int b = 0; b < 16; ++b) csum += hist4[tid * 16 + b];
            chunkSum[tid] = csum;
        }
        __syncthreads();
        {
            unsigned g = 0;
            for (int u = tid + 1; u < 256; ++u) g += chunkSum[u];
            unsigned csm = chunkSum[tid];
            if (g < KK && g + csm >= KK) {
                unsigned cum = g;
                #pragma unroll
                for (int b = 15; b >= 0; --b) {
                    unsigned c = hist4[tid * 16 + b];
                    if (cum + c >= KK) { sThreshKey = ((unsigned)(tid * 16 + b)) << 20; break; }
                    cum += c;
                }
            }
        }
        __syncthreads();
        const unsigned keyT = sThreshKey;
        __syncthreads();   // hist4 aliases cs -> drain before collection writes

        auto emit2 = [&](unsigned k, unsigned idx) {
            if (k >= keyT) {
                unsigned q = atomicAdd(&sCnt, 1u);
                if (q < 2048) cs[q] = ((unsigned long long)k << 32) | (unsigned)(~idx);
            }
        };
        if (tid < (int)p) emit2(fkey(rp[tid]), tid);
        for (unsigned i = tid; i < nb; i += 256) {
            float4n v = rp4[i];
            unsigned ia = p + 4u * i;
            emit2(fkey(v.x), ia + 0); emit2(fkey(v.y), ia + 1);
            emit2(fkey(v.z), ia + 2); emit2(fkey(v.w), ia + 3);
        }
        for (unsigned t = tail0 + tid; t < VV; t += 256) emit2(fkey(rp[t]), t);
        __syncthreads();
        unsigned n1 = sCnt; if (n1 > 2048) n1 = 2048;
        P = 256; while (P < n1) P <<= 1;
        for (unsigned i = n1 + tid; i < P; i += 256) cs[i] = 0ull;
        __syncthreads();
    }

    // ---- bitonic sort descending on composite (key<<32 | ~idx) ----
    for (unsigned k = 2; k <= P; k <<= 1) {
        for (unsigned jj = k >> 1; jj > 0; jj >>= 1) {
            for (unsigned i2 = tid; i2 < P; i2 += 256) {
                unsigned l = i2 ^ jj;
                if (l > i2) {
                    unsigned long long a = cs[i2], b = cs[l];
                    bool up = ((i2 & k) == 0);
                    if (up ? (a < b) : (a > b)) { cs[i2] = b; cs[l] = a; }
                }
            }
            __syncthreads();
        }
    }

    // ---- epilogue: proposal value at the K selected ids ----
    if (tid < KK) {
        float gxcb = 0.f, cbn = 0.f;
        #pragma unroll
        for (int e = 0; e < EE; ++e) { gxcb += gx_s[e] * cb_s[e]; cbn += cb_s[e] * cb_s[e]; }

        unsigned long long ck = cs[tid];
        unsigned v = ~((unsigned)ck);
        const float4* Wv = (const float4*)(W + (size_t)v * EE);
        float d1 = 0.f, d2 = 0.f, wn = 0.f;
        #pragma unroll
        for (int j2 = 0; j2 < 16; ++j2) {
            float4 w = Wv[j2];
            float a0 = gx_s[4*j2+0], a1 = gx_s[4*j2+1], a2 = gx_s[4*j2+2], a3 = gx_s[4*j2+3];
            float b0 = cb_s[4*j2+0], b1 = cb_s[4*j2+1], b2 = cb_s[4*j2+2], b3 = cb_s[4*j2+3];
            d1 += a0*w.x + a1*w.y + a2*w.z + a3*w.w;
            d2 += b0*w.x + b1*w.y + b2*w.z + b3*w.w;
            wn += w.x*w.x + w.y*w.y + w.z*w.z + w.w*w.w;
        }
        // dist = 0.5*(t1_1 - t1_2) + (t2_1 - 2*t2_2 + t2_3)/0.1 ; out = -dist / TEMP
        float unf = -(0.5f * (d1 - gxcb) + (wn - 2.0f * d2 + cbn) * 10.0f);
        out0[(size_t)row * KK + tid] = unf;
        out1[(size_t)row * KK + tid] = (float)v;
    }
}

extern "C" void kernel_launch(void* const* d_in, const int* in_sizes, int n_in,
                              void* d_out, int out_size, void* d_ws, size_t ws_size,
                              hipStream_t stream) {
    const float* gx = (const float*)d_in[0];      // [B,S,E]
    const float* cb = (const float*)d_in[1];      // [B,S,E]
    const float* W  = (const float*)d_in[2];      // [V,E]
    const float* lg = (const float*)d_in[3];      // [B,S,V]
    float* out0 = (float*)d_out;                       // filtered, 512000 floats
    float* out1 = out0 + (size_t)BB * SS * KK;         // ids as float, 512000

    // d_ws layout: cnt[4096] u32 (32 KB pad) ; cand[4096][FCAP] u64 (16.8 MB)
    unsigned* cnt = (unsigned*)d_ws;
    unsigned long long* cand = (unsigned long long*)((char*)d_ws + 32768);

    hipLaunchKernelGGL(filter_kernel, dim3(2 * NROWS), dim3(256), 0, stream,
                       lg, cand, cnt);
    hipLaunchKernelGGL(select_kernel, dim3(NROWS), dim3(256), 0, stream,
                       gx, cb, W, lg, cand, cnt, out0, out1);
}